// Round 7
// baseline (126.405 us; speedup 1.0000x reference)
//
#include <hip/hip_runtime.h>
#include <hip/hip_bf16.h>

typedef __attribute__((ext_vector_type(4))) float f32x4;
typedef __attribute__((ext_vector_type(8))) short bf16x8;
typedef unsigned short ushort_t;

#define T_LEN 8192
#define N_REFL 8187              // last valid phase index (phase arrays have 8188 elems)
#define XT_R 8224                // padded rows: 0..7 zero, 8..8199 = t+8, 8200..8223 zero
#define POSTRIDE 66              // u16 per phase row (boundary path only)
#define PH_U16 (80 * POSTRIDE)   // 5280 u16 per phase (boundary path only)
#define N_INT 4032               // interior blocks: 126 tiles * 2 g * 16 b  (= 8 * 504)
#define WS_XT_OFF 262144         // byte offset of xT in ws (wbf occupies first 212,992 B)

#define AS1(p) ((const __attribute__((address_space(1))) unsigned int*)(p))
#define AS3(p) ((__attribute__((address_space(3))) unsigned int*)(p))

__device__ __forceinline__ ushort_t f2bf(float f) {
    union { float f; unsigned u; } a; a.f = f;
    unsigned r = a.u + 0x7FFF + ((a.u >> 16) & 1);
    return (ushort_t)(r >> 16);
}

union bf2u { __hip_bfloat162 h; unsigned u; ushort_t s[2]; };

__device__ __forceinline__ unsigned pack_bf2(float a, float b) {
    bf2u x; x.h = __float22bfloat162_rn(make_float2(a, b));  // v_cvt_pk_bf16_f32
    return x.u;
}
__device__ __forceinline__ float bflo(unsigned u) {
    union { unsigned u; float f; } x; x.u = u << 16; return x.f;
}
__device__ __forceinline__ float bfhi(unsigned u) {
    union { unsigned u; float f; } x; x.u = u & 0xffff0000u; return x.f;
}
__device__ __forceinline__ float qgelu(float d) {
    return __fdividef(d, 1.f + __expf(-1.702f * d));
}
__device__ __forceinline__ float rot_lane(float v, int byteIdx) {
    int r = __builtin_amdgcn_ds_bpermute(byteIdx, __builtin_bit_cast(int, v));
    return __builtin_bit_cast(float, r);
}

// ---------------------------------------------------------------------------
// Repack w (128, 64, 13) f32 -> wbf[tap][o][c] bf16
__global__ void convert_w_kernel(const float* __restrict__ w, ushort_t* __restrict__ wbf) {
    int idx = blockIdx.x * 256 + threadIdx.x;
    if (idx >= 128 * 64 * 13) return;
    int tap = idx % 13;
    int c   = (idx / 13) & 63;
    int o   = idx / (13 * 64);
    wbf[(tap * 128 + o) * 64 + c] = f2bf(w[idx]);
}

// ---------------------------------------------------------------------------
// Transpose x[b][c][t] f32 -> xT[g*16+b][r][c ^ ((r&7)<<3)] bf16 (r = t+8),
// with zero rows 0..7 and 8200..8223. Coalesced on both sides.
__global__ __launch_bounds__(256)
void transpose_kernel(const float* __restrict__ x, ushort_t* __restrict__ xT) {
    __shared__ float ts[64 * 133];   // [t][128c], stride 133
    const int b   = blockIdx.y;
    const int t0  = blockIdx.x * 64;
    const int tid = threadIdx.x;

    const int cq = tid >> 4;          // 0..15
    const int tl = (tid & 15) * 4;    // 0..60
    #pragma unroll
    for (int cc = 0; cc < 8; ++cc) {
        int c = cq + 16 * cc;
        float4 v = *(const float4*)(x + ((size_t)(b * 128 + c)) * T_LEN + t0 + tl);
        ts[(tl + 0) * 133 + c] = v.x;
        ts[(tl + 1) * 133 + c] = v.y;
        ts[(tl + 2) * 133 + c] = v.z;
        ts[(tl + 3) * 133 + c] = v.w;
    }
    __syncthreads();

    #pragma unroll
    for (int it = 0; it < 4; ++it) {
        int wid   = tid + 256 * it;      // 0..1023 = 2g * 64t * 8chunk
        int g     = wid >> 9;
        int rem   = wid & 511;
        int t     = rem >> 3;
        int chunk = rem & 7;
        int r     = t0 + t + 8;
        const float* rp = ts + t * 133 + g * 64 + chunk * 8;
        uint4 pv;
        pv.x = pack_bf2(rp[0], rp[1]);
        pv.y = pack_bf2(rp[2], rp[3]);
        pv.z = pack_bf2(rp[4], rp[5]);
        pv.w = pack_bf2(rp[6], rp[7]);
        int swz = chunk ^ (r & 7);
        *(uint4*)(xT + ((size_t)(g * 16 + b) * XT_R + r) * 64 + swz * 8) = pv;
    }

    uint4 z; z.x = z.y = z.z = z.w = 0u;
    if (blockIdx.x == 0) {
        for (int i = tid; i < 128; i += 256) {          // 2g * 8r * 8chunk
            int g = i >> 6, j = i & 63;
            int r = j >> 3, chunk = j & 7;
            *(uint4*)(xT + ((size_t)(g * 16 + b) * XT_R + r) * 64 + chunk * 8) = z;
        }
    }
    if (blockIdx.x == 127) {
        for (int i = tid; i < 384; i += 256) {          // 2g * 24r * 8chunk
            int g = i / 192, j = i % 192;
            int r = 8200 + (j >> 3), chunk = j & 7;
            *(uint4*)(xT + ((size_t)(g * 16 + b) * XT_R + r) * 64 + chunk * 8) = z;
        }
    }
}

// ---------------------------------------------------------------------------
// Interior kernel: gload_lds stage (window shifted -2 rows for aligned stores)
// -> weight-pipelined MFMA -> reg epilogue -> full-line float4 stores.
__global__ __launch_bounds__(256, 4)
void fused_int_kernel(const ushort_t* __restrict__ xT, const ushort_t* __restrict__ wbf,
                      const float* __restrict__ bias, float* __restrict__ out) {
    __shared__ ushort_t xs[88 * 64];    // 11,264 B

    // XCD-aware swizzle: 4032 = 8 * 504; consecutive logical blocks share one XCD's L2.
    const int bx   = (blockIdx.x & 7) * 504 + (blockIdx.x >> 3);
    const int tid  = threadIdx.x;
    const int lane = tid & 63;
    const int wv   = tid >> 6;
    const int row  = lane & 15;
    const int kb   = lane >> 4;

    const int gb   = bx / 126;
    const int tile = 1 + (bx - gb * 126);
    const int g    = gb & 1;
    const int b    = gb >> 1;
    const int t0   = tile * 64;

    // stage xT rows [t0-2, t0+86) of plane (g,b): 11 x 1KB direct HBM->LDS.
    // xs row s holds x position (t0-10+s); baked swizzle phase = (s+6)&7.
    {
        const char* gsrc = (const char*)(xT + ((size_t)(g * 16 + b) * XT_R + (size_t)(t0 - 2)) * 64);
        for (int ch = wv; ch < 11; ch += 4) {
            __builtin_amdgcn_global_load_lds(AS1(gsrc + ch * 1024 + lane * 16),
                                             AS3((char*)xs + ch * 1024), 16, 0, 0);
        }
    }
    const int wo = g * 64 + wv * 16 + row;
    const float bo = bias[wo];

    // prefetch step-0 weights (independent of LDS) before the barrier
    bf16x8 cw0, cw1, cw2, nw0, nw1, nw2;
    cw0 = *(const bf16x8*)(wbf + (0 * 128 + wo) * 64 + kb * 8);
    cw1 = *(const bf16x8*)(wbf + (2 * 128 + wo) * 64 + kb * 8);
    cw2 = *(const bf16x8*)(wbf + (1 * 128 + wo) * 64 + kb * 8);
    __syncthreads();

    f32x4 accA[5], accL0[5], accL1[5];
    #pragma unroll
    for (int q = 0; q < 5; ++q) {
        accA[q]  = (f32x4){0.f, 0.f, 0.f, 0.f};
        accL0[q] = (f32x4){0.f, 0.f, 0.f, 0.f};
        accL1[q] = (f32x4){0.f, 0.f, 0.f, 0.f};
    }

    // 10 steps j = (u,h); weights for step j+1 prefetched during step j's MFMAs.
    #pragma unroll
    for (int j = 0; j < 10; ++j) {
        const int u = j >> 1, h = j & 1;
        if (j < 9) {
            const int un = (j + 1) >> 1, hn = (j + 1) & 1;
            nw0 = *(const bf16x8*)(wbf + ((3 * un + 0) * 128 + wo) * 64 + hn * 32 + kb * 8);
            if (un < 4) {
                nw1 = *(const bf16x8*)(wbf + ((3 * un + 2) * 128 + wo) * 64 + hn * 32 + kb * 8);
                nw2 = *(const bf16x8*)(wbf + ((3 * un + 1) * 128 + wo) * 64 + hn * 32 + kb * 8);
            }
        }
        #pragma unroll
        for (int q = 0; q < 5; ++q) {
            int s = 16 * q + row + u;
            const bf16x8 xa = *(const bf16x8*)(xs + s * 64 + ((h * 32 + kb * 8) ^ (((s + 6) & 7) << 3)));
            accA[q] = __builtin_amdgcn_mfma_f32_16x16x32_bf16(xa, cw0, accA[q], 0, 0, 0);
            if (u < 4) {
                accL0[q] = __builtin_amdgcn_mfma_f32_16x16x32_bf16(xa, cw1, accL0[q], 0, 0, 0);
                accL1[q] = __builtin_amdgcn_mfma_f32_16x16x32_bf16(xa, cw2, accL1[q], 0, 0, 0);
            }
        }
        cw0 = nw0; cw1 = nw1; cw2 = nw2;
    }

    // ---- in-register epilogue; output t = t0 + P - 8, P = 16q + 4kb + r ----
    const int upIdx = ((lane + 16) & 63) << 2;
    const int dnIdx = ((lane + 48) & 63) << 2;

    float u0[6], u1[6], d2m[5], d3m[5], lu[6], lv[6];
    #pragma unroll
    for (int q = 0; q < 5; ++q) {
        u0[q]  = rot_lane(accA[q][0], upIdx);
        u1[q]  = rot_lane(accA[q][1], upIdx);
        d2m[q] = rot_lane(accA[q][2], dnIdx);
        d3m[q] = rot_lane(accA[q][3], dnIdx);
        lu[q]  = rot_lane(accL0[q][0], upIdx);
        lv[q]  = rot_lane(accL1[q][0], upIdx);
    }
    u0[5] = 0.f; u1[5] = 0.f; lu[5] = 0.f; lv[5] = 0.f;

    const bool kbLT3 = (kb < 3);
    const bool kbGT0 = (kb > 0);
    const float c7bo = 7.f * bo;
    // aligned: (t0 - 8 + 4kb) % 4 == 0
    float* outBase = out + ((size_t)(b * 128 + wo)) * T_LEN + (t0 - 8 + 4 * kb);

    #pragma unroll
    for (int q = 0; q < 5; ++q) {
        float4 rv;
        #pragma unroll
        for (int r = 0; r < 4; ++r) {
            float A0 = accA[q][r];
            float Ap1 = (r < 3) ? accA[q][r + 1] : (kbLT3 ? u0[q] : u0[q + 1]);
            float Ap2 = (r == 0) ? accA[q][2]
                      : (r == 1) ? accA[q][3]
                      : (r == 2) ? (kbLT3 ? u0[q] : u0[q + 1])
                                 : (kbLT3 ? u1[q] : u1[q + 1]);
            float Am1 = (r > 0) ? accA[q][r - 1]
                                : (kbGT0 ? d3m[q] : (q > 0 ? d3m[q - 1] : 0.f));
            float Am2 = (r == 2) ? accA[q][0]
                      : (r == 3) ? accA[q][1]
                      : (r == 1) ? (kbGT0 ? d3m[q] : (q > 0 ? d3m[q - 1] : 0.f))
                                 : (kbGT0 ? d2m[q] : (q > 0 ? d2m[q - 1] : 0.f));
            float L0a = accL0[q][r];
            float L0b = (r < 3) ? accL0[q][r + 1] : (kbLT3 ? lu[q] : lu[q + 1]);
            float L1a = accL1[q][r];
            float L1b = (r < 3) ? accL1[q][r + 1] : (kbLT3 ? lv[q] : lv[q + 1]);

            float um = fmaxf(fmaxf(fmaxf(Am2, Am1), fmaxf(Ap1, Ap2)), A0);
            float res = 2.f * A0 + um + c7bo + (L0b + L0a) + (L1b + L1a)
                      + qgelu(L0b - L0a) + qgelu(L1b - L1a);
            ((float*)&rv)[r] = res;
        }
        // whole-fragment masks: q0 keeps kb>=2 (P>=8), q4 keeps kb<2 (P<72)
        bool ok = (q == 0) ? (kb >= 2) : (q == 4) ? (kb < 2) : true;
        if (ok) *(float4*)(outBase + 16 * q) = rv;
    }
}

// ---------------------------------------------------------------------------
// Boundary kernel (tiles 0 and 127, 64 blocks): LDS phase path, fed from xT pads.
__global__ __launch_bounds__(256, 4)
void fused_bnd_kernel(const ushort_t* __restrict__ xT, const ushort_t* __restrict__ wbf,
                      const float* __restrict__ bias, float* __restrict__ out) {
    __shared__ ushort_t smem[3 * PH_U16];   // 31,680 B; xs aliases the front
    ushort_t* xs = smem;

    const int idx  = blockIdx.x;
    const int tid  = threadIdx.x;
    const int lane = tid & 63;
    const int wv   = tid >> 6;
    const int row  = lane & 15;
    const int kb   = lane >> 4;

    const int tile = (idx & 1) ? 127 : 0;
    const int g    = (idx >> 1) & 1;
    const int b    = idx >> 2;
    const int t0    = tile * 64;
    const int mbase = t0 - 8;

    {
        const char* gsrc = (const char*)(xT + ((size_t)(g * 16 + b) * XT_R + (size_t)tile * 64) * 64);
        for (int ch = wv; ch < 11; ch += 4) {
            __builtin_amdgcn_global_load_lds(AS1(gsrc + ch * 1024 + lane * 16),
                                             AS3((char*)xs + ch * 1024), 16, 0, 0);
        }
    }
    const int wo = g * 64 + wv * 16 + row;
    const float bo = bias[wo];
    __syncthreads();

    f32x4 accA[5], accL0[5], accL1[5];
    #pragma unroll
    for (int q = 0; q < 5; ++q) {
        accA[q]  = (f32x4){0.f, 0.f, 0.f, 0.f};
        accL0[q] = (f32x4){0.f, 0.f, 0.f, 0.f};
        accL1[q] = (f32x4){0.f, 0.f, 0.f, 0.f};
    }

    #pragma unroll
    for (int u = 0; u < 5; ++u) {
        #pragma unroll
        for (int h = 0; h < 2; ++h) {
            bf16x8 wf0 = *(const bf16x8*)(wbf + ((3 * u + 0) * 128 + wo) * 64 + h * 32 + kb * 8);
            bf16x8 wf1 = {}, wf2 = {};
            if (u < 4) {
                wf1 = *(const bf16x8*)(wbf + ((3 * u + 2) * 128 + wo) * 64 + h * 32 + kb * 8);
                wf2 = *(const bf16x8*)(wbf + ((3 * u + 1) * 128 + wo) * 64 + h * 32 + kb * 8);
            }
            #pragma unroll
            for (int q = 0; q < 5; ++q) {
                int s = 16 * q + row + u;
                const bf16x8 xa = *(const bf16x8*)(xs + s * 64 + ((h * 32 + kb * 8) ^ ((s & 7) << 3)));
                accA[q] = __builtin_amdgcn_mfma_f32_16x16x32_bf16(xa, wf0, accA[q], 0, 0, 0);
                if (u < 4) {
                    accL0[q] = __builtin_amdgcn_mfma_f32_16x16x32_bf16(xa, wf1, accL0[q], 0, 0, 0);
                    accL1[q] = __builtin_amdgcn_mfma_f32_16x16x32_bf16(xa, wf2, accL1[q], 0, 0, 0);
                }
            }
        }
    }
    __syncthreads();   // done reading xs; safe to overwrite with phases

    #pragma unroll
    for (int q = 0; q < 5; ++q) {
        #pragma unroll
        for (int p = 0; p < 3; ++p) {
            const f32x4& a = (p == 0) ? accA[q] : (p == 1) ? accL0[q] : accL1[q];
            unsigned pa = pack_bf2(a[0] + bo, a[1] + bo);
            unsigned pb = pack_bf2(a[2] + bo, a[3] + bo);
            int base = p * PH_U16 + (16 * q + kb * 4) * POSTRIDE + wv * 16 + row;
            smem[base + 0 * POSTRIDE] = (ushort_t)(pa & 0xffff);
            smem[base + 1 * POSTRIDE] = (ushort_t)(pa >> 16);
            smem[base + 2 * POSTRIDE] = (ushort_t)(pb & 0xffff);
            smem[base + 3 * POSTRIDE] = (ushort_t)(pb >> 16);
        }
    }
    __syncthreads();

    const int tl = tid & 63;
    const int wq = tid >> 6;
    const int t  = t0 + tl;
    const ushort_t* phA  = smem;
    const ushort_t* phL0 = smem + PH_U16;
    const ushort_t* phL1 = smem + 2 * PH_U16;
    float* outp = out + ((size_t)b * 128 + (size_t)g * 64) * T_LEN + t;

    int  s5[5];
    bool in5[5];
    #pragma unroll
    for (int dt = 0; dt < 5; ++dt) {
        int tp = t + dt - 2;
        in5[dt] = ((unsigned)tp < (unsigned)T_LEN);
        int ix = tp - 2;
        ix = (ix < 0) ? -ix : ix;
        ix = (ix > N_REFL) ? (2 * N_REFL - ix) : ix;
        s5[dt] = ix - mbase;
    }
    const int sC = s5[2];
    for (int i = 0; i < 8; ++i) {
        int o = 2 * wq + 8 * i;
        unsigned av[5];
        #pragma unroll
        for (int dt = 0; dt < 5; ++dt)
            av[dt] = *(const unsigned*)(phA + s5[dt] * POSTRIDE + o);
        unsigned l0a = *(const unsigned*)(phL0 + (sC    ) * POSTRIDE + o);
        unsigned l0b = *(const unsigned*)(phL0 + (sC + 1) * POSTRIDE + o);
        unsigned l1a = *(const unsigned*)(phL1 + (sC    ) * POSTRIDE + o);
        unsigned l1b = *(const unsigned*)(phL1 + (sC + 1) * POSTRIDE + o);

        float xm_l = bflo(av[2]), xm_h = bfhi(av[2]);
        float um_l = -1e30f, um_h = -1e30f;
        #pragma unroll
        for (int dt = 0; dt < 5; ++dt) {
            um_l = fmaxf(um_l, in5[dt] ? bflo(av[dt]) : 0.f);
            um_h = fmaxf(um_h, in5[dt] ? bfhi(av[dt]) : 0.f);
        }
        float l0al = bflo(l0a), l0bl = bflo(l0b), l1al = bflo(l1a), l1bl = bflo(l1b);
        float l0ah = bfhi(l0a), l0bh = bfhi(l0b), l1ah = bfhi(l1a), l1bh = bfhi(l1b);

        float rl = 2.f * xm_l + um_l + (l0bl + l0al) + qgelu(l0bl - l0al)
                                     + (l1bl + l1al) + qgelu(l1bl - l1al);
        float rh = 2.f * xm_h + um_h + (l0bh + l0ah) + qgelu(l0bh - l0ah)
                                     + (l1bh + l1ah) + qgelu(l1bh - l1ah);
        outp[(size_t)(o    ) * T_LEN] = rl;
        outp[(size_t)(o + 1) * T_LEN] = rh;
    }
}

// ---------------------------------------------------------------------------
// Fallback (R3 verbatim): single fused kernel with LDS staging, used if ws too small.
__global__ __launch_bounds__(256, 4)
void fused_trconv_r3(const float* __restrict__ x, const ushort_t* __restrict__ wbf,
                     const float* __restrict__ bias, float* __restrict__ out) {
    __shared__ ushort_t smem[3 * PH_U16];
    ushort_t* xs = smem;

    const int bx    = blockIdx.x;
    const int tile  = bx & 127;
    const int g     = (bx >> 7) & 1;
    const int b     = bx >> 8;
    const int t0    = tile * 64;
    const int mbase = t0 - 8;
    const int tid   = threadIdx.x;

    const float* xg = x + ((size_t)b * 128 + (size_t)g * 64) * T_LEN;
    for (int cid = tid; cid < 64 * 22; cid += 256) {
        int c  = cid & 63;
        int kc = cid >> 6;
        int s0 = kc * 4;
        int m0 = mbase + s0;
        const float* src = xg + (size_t)c * T_LEN + m0;
        float v0, v1, v2, v3;
        if (m0 >= 0 && m0 + 3 < T_LEN) {
            float4 v = *(const float4*)src;
            v0 = v.x; v1 = v.y; v2 = v.z; v3 = v.w;
        } else {
            v0 = (m0 + 0 >= 0 && m0 + 0 < T_LEN) ? src[0] : 0.f;
            v1 = (m0 + 1 >= 0 && m0 + 1 < T_LEN) ? src[1] : 0.f;
            v2 = (m0 + 2 >= 0 && m0 + 2 < T_LEN) ? src[2] : 0.f;
            v3 = (m0 + 3 >= 0 && m0 + 3 < T_LEN) ? src[3] : 0.f;
        }
        unsigned p01 = pack_bf2(v0, v1);
        unsigned p23 = pack_bf2(v2, v3);
        xs[(s0 + 0) * 64 + (c ^ (((s0 + 0) & 7) << 3))] = (ushort_t)(p01 & 0xffff);
        xs[(s0 + 1) * 64 + (c ^ (((s0 + 1) & 7) << 3))] = (ushort_t)(p01 >> 16);
        xs[(s0 + 2) * 64 + (c ^ (((s0 + 2) & 7) << 3))] = (ushort_t)(p23 & 0xffff);
        xs[(s0 + 3) * 64 + (c ^ (((s0 + 3) & 7) << 3))] = (ushort_t)(p23 >> 16);
    }
    __syncthreads();

    const int lane = tid & 63;
    const int wv   = tid >> 6;
    const int row  = lane & 15;
    const int kb   = lane >> 4;

    f32x4 accA[5], accL0[5], accL1[5];
    #pragma unroll
    for (int q = 0; q < 5; ++q) {
        accA[q]  = (f32x4){0.f, 0.f, 0.f, 0.f};
        accL0[q] = (f32x4){0.f, 0.f, 0.f, 0.f};
        accL1[q] = (f32x4){0.f, 0.f, 0.f, 0.f};
    }
    const int wo = g * 64 + wv * 16 + row;

    #pragma unroll
    for (int u = 0; u < 5; ++u) {
        #pragma unroll
        for (int h = 0; h < 2; ++h) {
            bf16x8 wf0 = *(const bf16x8*)(wbf + ((3 * u + 0) * 128 + wo) * 64 + h * 32 + kb * 8);
            bf16x8 wf1 = {}, wf2 = {};
            if (u < 4) {
                wf1 = *(const bf16x8*)(wbf + ((3 * u + 2) * 128 + wo) * 64 + h * 32 + kb * 8);
                wf2 = *(const bf16x8*)(wbf + ((3 * u + 1) * 128 + wo) * 64 + h * 32 + kb * 8);
            }
            #pragma unroll
            for (int q = 0; q < 5; ++q) {
                int s = 16 * q + row + u;
                const bf16x8 xa = *(const bf16x8*)(xs + s * 64 + ((h * 32 + kb * 8) ^ ((s & 7) << 3)));
                accA[q] = __builtin_amdgcn_mfma_f32_16x16x32_bf16(xa, wf0, accA[q], 0, 0, 0);
                if (u < 4) {
                    accL0[q] = __builtin_amdgcn_mfma_f32_16x16x32_bf16(xa, wf1, accL0[q], 0, 0, 0);
                    accL1[q] = __builtin_amdgcn_mfma_f32_16x16x32_bf16(xa, wf2, accL1[q], 0, 0, 0);
                }
            }
        }
    }
    const float bo = bias[wo];

    if (tile != 0 && tile != 127) {
        const int upIdx = ((lane + 16) & 63) << 2;
        const int dnIdx = ((lane + 48) & 63) << 2;

        float u0[6], u1[6], d2m[5], d3m[5], lu[6], lv[6];
        #pragma unroll
        for (int q = 0; q < 5; ++q) {
            u0[q]  = rot_lane(accA[q][0], upIdx);
            u1[q]  = rot_lane(accA[q][1], upIdx);
            d2m[q] = rot_lane(accA[q][2], dnIdx);
            d3m[q] = rot_lane(accA[q][3], dnIdx);
            lu[q]  = rot_lane(accL0[q][0], upIdx);
            lv[q]  = rot_lane(accL1[q][0], upIdx);
        }
        u0[5] = 0.f; u1[5] = 0.f; lu[5] = 0.f; lv[5] = 0.f;

        const bool kbLT3 = (kb < 3);
        const bool kbGT0 = (kb > 0);
        const float c7bo = 7.f * bo;
        float* outBase = out + ((size_t)(b * 128 + wo)) * T_LEN + (t0 - 6 + 4 * kb);

        #pragma unroll
        for (int q = 0; q < 5; ++q) {
            #pragma unroll
            for (int r = 0; r < 4; ++r) {
                float A0 = accA[q][r];
                float Ap1 = (r < 3) ? accA[q][r + 1] : (kbLT3 ? u0[q] : u0[q + 1]);
                float Ap2 = (r == 0) ? accA[q][2]
                          : (r == 1) ? accA[q][3]
                          : (r == 2) ? (kbLT3 ? u0[q] : u0[q + 1])
                                     : (kbLT3 ? u1[q] : u1[q + 1]);
                float Am1 = (r > 0) ? accA[q][r - 1]
                                    : (kbGT0 ? d3m[q] : (q > 0 ? d3m[q - 1] : 0.f));
                float Am2 = (r == 2) ? accA[q][0]
                          : (r == 3) ? accA[q][1]
                          : (r == 1) ? (kbGT0 ? d3m[q] : (q > 0 ? d3m[q - 1] : 0.f))
                                     : (kbGT0 ? d2m[q] : (q > 0 ? d2m[q - 1] : 0.f));
                float L0a = accL0[q][r];
                float L0b = (r < 3) ? accL0[q][r + 1] : (kbLT3 ? lu[q] : lu[q + 1]);
                float L1a = accL1[q][r];
                float L1b = (r < 3) ? accL1[q][r + 1] : (kbLT3 ? lv[q] : lv[q + 1]);

                float um = fmaxf(fmaxf(fmaxf(Am2, Am1), fmaxf(Ap1, Ap2)), A0);
                float res = 2.f * A0 + um + c7bo + (L0b + L0a) + (L1b + L1a)
                          + qgelu(L0b - L0a) + qgelu(L1b - L1a);

                bool ok = true;
                if (q == 0) ok = (4 * kb + r) >= 6;
                if (q == 4) ok = (4 * kb + r) <= 5;
                if (ok) outBase[16 * q + r] = res;
            }
        }
    } else {
        __syncthreads();
        #pragma unroll
        for (int q = 0; q < 5; ++q) {
            #pragma unroll
            for (int p = 0; p < 3; ++p) {
                const f32x4& a = (p == 0) ? accA[q] : (p == 1) ? accL0[q] : accL1[q];
                unsigned pa = pack_bf2(a[0] + bo, a[1] + bo);
                unsigned pb = pack_bf2(a[2] + bo, a[3] + bo);
                int base = p * PH_U16 + (16 * q + kb * 4) * POSTRIDE + wv * 16 + row;
                smem[base + 0 * POSTRIDE] = (ushort_t)(pa & 0xffff);
                smem[base + 1 * POSTRIDE] = (ushort_t)(pa >> 16);
                smem[base + 2 * POSTRIDE] = (ushort_t)(pb & 0xffff);
                smem[base + 3 * POSTRIDE] = (ushort_t)(pb >> 16);
            }
        }
        __syncthreads();

        const int tl = tid & 63;
        const int wq = tid >> 6;
        const int t  = t0 + tl;
        const ushort_t* phA  = smem;
        const ushort_t* phL0 = smem + PH_U16;
        const ushort_t* phL1 = smem + 2 * PH_U16;
        float* outp = out + ((size_t)b * 128 + (size_t)g * 64) * T_LEN + t;

        int  s5[5];
        bool in5[5];
        #pragma unroll
        for (int dt = 0; dt < 5; ++dt) {
            int tp = t + dt - 2;
            in5[dt] = ((unsigned)tp < (unsigned)T_LEN);
            int ix = tp - 2;
            ix = (ix < 0) ? -ix : ix;
            ix = (ix > N_REFL) ? (2 * N_REFL - ix) : ix;
            s5[dt] = ix - mbase;
        }
        const int sC = s5[2];
        for (int i = 0; i < 8; ++i) {
            int o = 2 * wq + 8 * i;
            unsigned av[5];
            #pragma unroll
            for (int dt = 0; dt < 5; ++dt)
                av[dt] = *(const unsigned*)(phA + s5[dt] * POSTRIDE + o);
            unsigned l0a = *(const unsigned*)(phL0 + (sC    ) * POSTRIDE + o);
            unsigned l0b = *(const unsigned*)(phL0 + (sC + 1) * POSTRIDE + o);
            unsigned l1a = *(const unsigned*)(phL1 + (sC    ) * POSTRIDE + o);
            unsigned l1b = *(const unsigned*)(phL1 + (sC + 1) * POSTRIDE + o);

            float xm_l = bflo(av[2]), xm_h = bfhi(av[2]);
            float um_l = -1e30f, um_h = -1e30f;
            #pragma unroll
            for (int dt = 0; dt < 5; ++dt) {
                um_l = fmaxf(um_l, in5[dt] ? bflo(av[dt]) : 0.f);
                um_h = fmaxf(um_h, in5[dt] ? bfhi(av[dt]) : 0.f);
            }
            float l0al = bflo(l0a), l0bl = bflo(l0b), l1al = bflo(l1a), l1bl = bflo(l1b);
            float l0ah = bfhi(l0a), l0bh = bfhi(l0b), l1ah = bfhi(l1a), l1bh = bfhi(l1b);

            float rl = 2.f * xm_l + um_l + (l0bl + l0al) + qgelu(l0bl - l0al)
                                         + (l1bl + l1al) + qgelu(l1bl - l1al);
            float rh = 2.f * xm_h + um_h + (l0bh + l0ah) + qgelu(l0bh - l0ah)
                                         + (l1bh + l1ah) + qgelu(l1bh - l1ah);
            outp[(size_t)(o    ) * T_LEN] = rl;
            outp[(size_t)(o + 1) * T_LEN] = rh;
        }
    }
}

extern "C" void kernel_launch(void* const* d_in, const int* in_sizes, int n_in,
                              void* d_out, int out_size, void* d_ws, size_t ws_size,
                              hipStream_t stream) {
    const float* x    = (const float*)d_in[0];
    const float* w    = (const float*)d_in[1];
    const float* bias = (const float*)d_in[2];
    float* out        = (float*)d_out;
    ushort_t* wbf     = (ushort_t*)d_ws;    // 13*128*64*2 = 212,992 B

    hipLaunchKernelGGL(convert_w_kernel, dim3(416), dim3(256), 0, stream, w, wbf);

    const size_t need = WS_XT_OFF + (size_t)32 * XT_R * 64 * 2;  // ~33.9 MB
    if (ws_size >= need) {
        ushort_t* xT = (ushort_t*)((char*)d_ws + WS_XT_OFF);
        hipLaunchKernelGGL(transpose_kernel, dim3(128, 16), dim3(256), 0, stream, x, xT);
        hipLaunchKernelGGL(fused_int_kernel, dim3(N_INT), dim3(256), 0, stream,
                           xT, wbf, bias, out);
        hipLaunchKernelGGL(fused_bnd_kernel, dim3(64), dim3(256), 0, stream,
                           xT, wbf, bias, out);
    } else {
        hipLaunchKernelGGL(fused_trconv_r3, dim3(16 * 2 * 128), dim3(256), 0, stream,
                           x, wbf, bias, out);
    }
}

// Round 8
// 125.573 us; speedup vs baseline: 1.0066x; 1.0066x over previous
//
#include <hip/hip_runtime.h>
#include <hip/hip_bf16.h>

typedef __attribute__((ext_vector_type(4))) float f32x4;
typedef __attribute__((ext_vector_type(8))) short bf16x8;
typedef unsigned short ushort_t;

#define T_LEN 8192
#define N_REFL 8187              // last valid phase index (phase arrays have 8188 elems)
#define POSTRIDE 66              // u16 per phase row (boundary path only)
#define PH_U16 (80 * POSTRIDE)   // 5280 u16 per phase (boundary path only)
#define N_INT 4032               // interior blocks: 126 tiles * 2 g * 16 b
#define WS_WNEW_OFF 262144       // wnew offset in ws (wold occupies first 212,992 B)

__device__ __forceinline__ ushort_t f2bf(float f) {
    union { float f; unsigned u; } a; a.f = f;
    unsigned r = a.u + 0x7FFF + ((a.u >> 16) & 1);
    return (ushort_t)(r >> 16);
}

union bf2u { __hip_bfloat162 h; unsigned u; ushort_t s[2]; };

__device__ __forceinline__ unsigned pack_bf2(float a, float b) {
    bf2u x; x.h = __float22bfloat162_rn(make_float2(a, b));  // v_cvt_pk_bf16_f32
    return x.u;
}
__device__ __forceinline__ float bflo(unsigned u) {
    union { unsigned u; float f; } x; x.u = u << 16; return x.f;
}
__device__ __forceinline__ float bfhi(unsigned u) {
    union { unsigned u; float f; } x; x.u = u & 0xffff0000u; return x.f;
}
// quick_gelu(d) = d * sigmoid(1.702 d) = d / (1 + 2^(-2.4553418 d))
__device__ __forceinline__ float qgelu(float d) {
    return d * __frcp_rn(1.f + exp2f(-2.4553418f * d));
}
__device__ __forceinline__ float qgelu2(float d) {   // boundary path (keep R3 form)
    return __fdividef(d, 1.f + __expf(-1.702f * d));
}
__device__ __forceinline__ float rot_lane(float v, int byteIdx) {
    int r = __builtin_amdgcn_ds_bpermute(byteIdx, __builtin_bit_cast(int, v));
    return __builtin_bit_cast(float, r);
}

// ---------------------------------------------------------------------------
// w (128,64,13) f32 -> wold[tap][o][c] (13 slots) AND wnew[p*5+k][o][c] (20 slots)
// phases p: 0=A (w[3k]); 1=S (2A + L0 + L0<<1 + L1 + L1<<1); 2=D0 (L0<<1 - L0); 3=D1.
__global__ void convert_w_kernel(const float* __restrict__ w,
                                 ushort_t* __restrict__ wold,
                                 ushort_t* __restrict__ wnew) {
    int idx = blockIdx.x * 256 + threadIdx.x;   // o*64 + c
    if (idx >= 8192) return;
    int o = idx >> 6, c = idx & 63;
    const float* wp = w + (size_t)idx * 13;
    float t[13];
    #pragma unroll
    for (int k = 0; k < 13; ++k) t[k] = wp[k];
    #pragma unroll
    for (int k = 0; k < 13; ++k) wold[(k * 128 + o) * 64 + c] = f2bf(t[k]);
    #pragma unroll
    for (int k = 0; k < 5; ++k) {
        float a   = t[3 * k];
        float l0k = (k <= 3) ? t[3 * k + 2] : 0.f;   // cL0[k]
        float l1k = (k <= 3) ? t[3 * k + 1] : 0.f;   // cL1[k]
        float l0m = (k >= 1) ? t[3 * k - 1] : 0.f;   // cL0[k-1]
        float l1m = (k >= 1) ? t[3 * k - 2] : 0.f;   // cL1[k-1]
        wnew[((0 * 5 + k) * 128 + o) * 64 + c] = f2bf(a);
        wnew[((1 * 5 + k) * 128 + o) * 64 + c] = f2bf(2.f * a + l0k + l0m + l1k + l1m);
        wnew[((2 * 5 + k) * 128 + o) * 64 + c] = f2bf(l0m - l0k);
        wnew[((3 * 5 + k) * 128 + o) * 64 + c] = f2bf(l1m - l1k);
    }
}

// ---------------------------------------------------------------------------
// Interior kernel (tiles 1..126): LDS stage (no bounds checks) -> 4-phase MFMA
// (A,S,D0,D1 share the same 5 shifted LDS reads) -> lean in-register epilogue.
__global__ __launch_bounds__(256, 3)
void fused_int_kernel(const float* __restrict__ x, const ushort_t* __restrict__ wnew,
                      const float* __restrict__ bias, float* __restrict__ out) {
    __shared__ ushort_t xs[88 * 64];    // 11,264 B, XOR-swizzled

    const int bx   = blockIdx.x;
    const int tid  = threadIdx.x;
    const int lane = tid & 63;
    const int wv   = tid >> 6;
    const int row  = lane & 15;
    const int kb   = lane >> 4;

    const int gb   = bx / 126;
    const int tile = 1 + (bx - gb * 126);
    const int g    = gb & 1;
    const int b    = gb >> 1;
    const int t0   = tile * 64;
    const int mbase = t0 - 8;            // in-range: 56 .. 8143 for all interior tiles

    // ---- stage x[group ch][mbase..mbase+87] -> xs[s][c^((s&7)<<3)] bf16 ----
    const float* xg = x + ((size_t)b * 128 + (size_t)g * 64) * T_LEN;
    for (int cid = tid; cid < 64 * 22; cid += 256) {
        int c  = cid & 63;
        int s0 = (cid >> 6) * 4;
        float4 v = *(const float4*)(xg + (size_t)c * T_LEN + (mbase + s0));
        unsigned p01 = pack_bf2(v.x, v.y);
        unsigned p23 = pack_bf2(v.z, v.w);
        xs[(s0 + 0) * 64 + (c ^ (((s0 + 0) & 7) << 3))] = (ushort_t)(p01 & 0xffff);
        xs[(s0 + 1) * 64 + (c ^ (((s0 + 1) & 7) << 3))] = (ushort_t)(p01 >> 16);
        xs[(s0 + 2) * 64 + (c ^ (((s0 + 2) & 7) << 3))] = (ushort_t)(p23 & 0xffff);
        xs[(s0 + 3) * 64 + (c ^ (((s0 + 3) & 7) << 3))] = (ushort_t)(p23 >> 16);
    }
    const int wo = g * 64 + wv * 16 + row;
    const float bo = bias[wo];
    __syncthreads();

    f32x4 accA[5], accS[5], accD0[5], accD1[5];
    #pragma unroll
    for (int q = 0; q < 5; ++q) {
        accA[q]  = (f32x4){0.f, 0.f, 0.f, 0.f};
        accS[q]  = (f32x4){0.f, 0.f, 0.f, 0.f};
        accD0[q] = (f32x4){0.f, 0.f, 0.f, 0.f};
        accD1[q] = (f32x4){0.f, 0.f, 0.f, 0.f};
    }

    #pragma unroll
    for (int u = 0; u < 5; ++u) {
        #pragma unroll
        for (int h = 0; h < 2; ++h) {
            const int wbase = h * 32 + kb * 8;
            bf16x8 wfA = *(const bf16x8*)(wnew + ((0 * 5 + u) * 128 + wo) * 64 + wbase);
            bf16x8 wfS = *(const bf16x8*)(wnew + ((1 * 5 + u) * 128 + wo) * 64 + wbase);
            bf16x8 wf0 = *(const bf16x8*)(wnew + ((2 * 5 + u) * 128 + wo) * 64 + wbase);
            bf16x8 wf1 = *(const bf16x8*)(wnew + ((3 * 5 + u) * 128 + wo) * 64 + wbase);
            #pragma unroll
            for (int q = 0; q < 5; ++q) {
                int s = 16 * q + row + u;
                const bf16x8 xa = *(const bf16x8*)(xs + s * 64 + (wbase ^ ((s & 7) << 3)));
                accA[q]  = __builtin_amdgcn_mfma_f32_16x16x32_bf16(xa, wfA, accA[q],  0, 0, 0);
                accS[q]  = __builtin_amdgcn_mfma_f32_16x16x32_bf16(xa, wfS, accS[q],  0, 0, 0);
                accD0[q] = __builtin_amdgcn_mfma_f32_16x16x32_bf16(xa, wf0, accD0[q], 0, 0, 0);
                accD1[q] = __builtin_amdgcn_mfma_f32_16x16x32_bf16(xa, wf1, accD1[q], 0, 0, 0);
            }
        }
    }

    // ---- epilogue: only A needs neighbors (bpermute); S/D0/D1 used in place ----
    const int upIdx = ((lane + 16) & 63) << 2;
    const int dnIdx = ((lane + 48) & 63) << 2;

    float u0[6], u1[6], d2m[5], d3m[5];
    #pragma unroll
    for (int q = 0; q < 5; ++q) {
        u0[q]  = rot_lane(accA[q][0], upIdx);
        u1[q]  = rot_lane(accA[q][1], upIdx);
        d2m[q] = rot_lane(accA[q][2], dnIdx);
        d3m[q] = rot_lane(accA[q][3], dnIdx);
    }
    u0[5] = 0.f; u1[5] = 0.f;

    const bool kbLT3 = (kb < 3);
    const bool kbGT0 = (kb > 0);
    const float c7bo = 7.f * bo;
    float* outBase = out + ((size_t)(b * 128 + wo)) * T_LEN + (t0 - 6 + 4 * kb);

    #pragma unroll
    for (int q = 0; q < 5; ++q) {
        #pragma unroll
        for (int r = 0; r < 4; ++r) {
            float A0 = accA[q][r];
            float Ap1 = (r < 3) ? accA[q][r + 1] : (kbLT3 ? u0[q] : u0[q + 1]);
            float Ap2 = (r == 0) ? accA[q][2]
                      : (r == 1) ? accA[q][3]
                      : (r == 2) ? (kbLT3 ? u0[q] : u0[q + 1])
                                 : (kbLT3 ? u1[q] : u1[q + 1]);
            float Am1 = (r > 0) ? accA[q][r - 1]
                                : (kbGT0 ? d3m[q] : (q > 0 ? d3m[q - 1] : 0.f));
            float Am2 = (r == 2) ? accA[q][0]
                      : (r == 3) ? accA[q][1]
                      : (r == 1) ? (kbGT0 ? d3m[q] : (q > 0 ? d3m[q - 1] : 0.f))
                                 : (kbGT0 ? d2m[q] : (q > 0 ? d2m[q - 1] : 0.f));

            float um  = fmaxf(fmaxf(fmaxf(Am2, Am1), A0), fmaxf(Ap1, Ap2));
            float res = accS[q][r] + um + c7bo + qgelu(accD0[q][r]) + qgelu(accD1[q][r]);

            bool ok = true;
            if (q == 0) ok = (4 * kb + r) >= 6;
            if (q == 4) ok = (4 * kb + r) <= 5;
            if (ok) outBase[16 * q + r] = res;
        }
    }
}

// ---------------------------------------------------------------------------
// Boundary kernel (tiles 0 and 127, 64 blocks): proven R3 path, old weights.
__global__ __launch_bounds__(256, 4)
void fused_bnd_kernel(const float* __restrict__ x, const ushort_t* __restrict__ wbf,
                      const float* __restrict__ bias, float* __restrict__ out) {
    __shared__ ushort_t smem[3 * PH_U16];   // 31,680 B
    ushort_t* xs = smem;

    const int idx  = blockIdx.x;
    const int tid  = threadIdx.x;
    const int lane = tid & 63;
    const int wv   = tid >> 6;
    const int row  = lane & 15;
    const int kb   = lane >> 4;

    const int tile = (idx & 1) ? 127 : 0;
    const int g    = (idx >> 1) & 1;
    const int b    = idx >> 2;
    const int t0    = tile * 64;
    const int mbase = t0 - 8;

    const float* xg = x + ((size_t)b * 128 + (size_t)g * 64) * T_LEN;
    for (int cid = tid; cid < 64 * 22; cid += 256) {
        int c  = cid & 63;
        int s0 = (cid >> 6) * 4;
        int m0 = mbase + s0;
        const float* src = xg + (size_t)c * T_LEN + m0;
        float v0, v1, v2, v3;
        if (m0 >= 0 && m0 + 3 < T_LEN) {
            float4 v = *(const float4*)src;
            v0 = v.x; v1 = v.y; v2 = v.z; v3 = v.w;
        } else {
            v0 = ((unsigned)(m0 + 0) < (unsigned)T_LEN) ? src[0] : 0.f;
            v1 = ((unsigned)(m0 + 1) < (unsigned)T_LEN) ? src[1] : 0.f;
            v2 = ((unsigned)(m0 + 2) < (unsigned)T_LEN) ? src[2] : 0.f;
            v3 = ((unsigned)(m0 + 3) < (unsigned)T_LEN) ? src[3] : 0.f;
        }
        unsigned p01 = pack_bf2(v0, v1);
        unsigned p23 = pack_bf2(v2, v3);
        xs[(s0 + 0) * 64 + (c ^ (((s0 + 0) & 7) << 3))] = (ushort_t)(p01 & 0xffff);
        xs[(s0 + 1) * 64 + (c ^ (((s0 + 1) & 7) << 3))] = (ushort_t)(p01 >> 16);
        xs[(s0 + 2) * 64 + (c ^ (((s0 + 2) & 7) << 3))] = (ushort_t)(p23 & 0xffff);
        xs[(s0 + 3) * 64 + (c ^ (((s0 + 3) & 7) << 3))] = (ushort_t)(p23 >> 16);
    }
    __syncthreads();

    f32x4 accA[5], accL0[5], accL1[5];
    #pragma unroll
    for (int q = 0; q < 5; ++q) {
        accA[q]  = (f32x4){0.f, 0.f, 0.f, 0.f};
        accL0[q] = (f32x4){0.f, 0.f, 0.f, 0.f};
        accL1[q] = (f32x4){0.f, 0.f, 0.f, 0.f};
    }
    const int wo = g * 64 + wv * 16 + row;

    #pragma unroll
    for (int u = 0; u < 5; ++u) {
        #pragma unroll
        for (int h = 0; h < 2; ++h) {
            bf16x8 wf0 = *(const bf16x8*)(wbf + ((3 * u + 0) * 128 + wo) * 64 + h * 32 + kb * 8);
            bf16x8 wf1 = {}, wf2 = {};
            if (u < 4) {
                wf1 = *(const bf16x8*)(wbf + ((3 * u + 2) * 128 + wo) * 64 + h * 32 + kb * 8);
                wf2 = *(const bf16x8*)(wbf + ((3 * u + 1) * 128 + wo) * 64 + h * 32 + kb * 8);
            }
            #pragma unroll
            for (int q = 0; q < 5; ++q) {
                int s = 16 * q + row + u;
                const bf16x8 xa = *(const bf16x8*)(xs + s * 64 + ((h * 32 + kb * 8) ^ ((s & 7) << 3)));
                accA[q] = __builtin_amdgcn_mfma_f32_16x16x32_bf16(xa, wf0, accA[q], 0, 0, 0);
                if (u < 4) {
                    accL0[q] = __builtin_amdgcn_mfma_f32_16x16x32_bf16(xa, wf1, accL0[q], 0, 0, 0);
                    accL1[q] = __builtin_amdgcn_mfma_f32_16x16x32_bf16(xa, wf2, accL1[q], 0, 0, 0);
                }
            }
        }
    }
    const float bo = bias[wo];
    __syncthreads();

    #pragma unroll
    for (int q = 0; q < 5; ++q) {
        #pragma unroll
        for (int p = 0; p < 3; ++p) {
            const f32x4& a = (p == 0) ? accA[q] : (p == 1) ? accL0[q] : accL1[q];
            unsigned pa = pack_bf2(a[0] + bo, a[1] + bo);
            unsigned pb = pack_bf2(a[2] + bo, a[3] + bo);
            int base = p * PH_U16 + (16 * q + kb * 4) * POSTRIDE + wv * 16 + row;
            smem[base + 0 * POSTRIDE] = (ushort_t)(pa & 0xffff);
            smem[base + 1 * POSTRIDE] = (ushort_t)(pa >> 16);
            smem[base + 2 * POSTRIDE] = (ushort_t)(pb & 0xffff);
            smem[base + 3 * POSTRIDE] = (ushort_t)(pb >> 16);
        }
    }
    __syncthreads();

    const int tl = tid & 63;
    const int wq = tid >> 6;
    const int t  = t0 + tl;
    const ushort_t* phA  = smem;
    const ushort_t* phL0 = smem + PH_U16;
    const ushort_t* phL1 = smem + 2 * PH_U16;
    float* outp = out + ((size_t)b * 128 + (size_t)g * 64) * T_LEN + t;

    int  s5[5];
    bool in5[5];
    #pragma unroll
    for (int dt = 0; dt < 5; ++dt) {
        int tp = t + dt - 2;
        in5[dt] = ((unsigned)tp < (unsigned)T_LEN);
        int ix = tp - 2;
        ix = (ix < 0) ? -ix : ix;
        ix = (ix > N_REFL) ? (2 * N_REFL - ix) : ix;
        s5[dt] = ix - mbase;
    }
    const int sC = s5[2];
    for (int i = 0; i < 8; ++i) {
        int o = 2 * wq + 8 * i;
        unsigned av[5];
        #pragma unroll
        for (int dt = 0; dt < 5; ++dt)
            av[dt] = *(const unsigned*)(phA + s5[dt] * POSTRIDE + o);
        unsigned l0a = *(const unsigned*)(phL0 + (sC    ) * POSTRIDE + o);
        unsigned l0b = *(const unsigned*)(phL0 + (sC + 1) * POSTRIDE + o);
        unsigned l1a = *(const unsigned*)(phL1 + (sC    ) * POSTRIDE + o);
        unsigned l1b = *(const unsigned*)(phL1 + (sC + 1) * POSTRIDE + o);

        float xm_l = bflo(av[2]), xm_h = bfhi(av[2]);
        float um_l = -1e30f, um_h = -1e30f;
        #pragma unroll
        for (int dt = 0; dt < 5; ++dt) {
            um_l = fmaxf(um_l, in5[dt] ? bflo(av[dt]) : 0.f);
            um_h = fmaxf(um_h, in5[dt] ? bfhi(av[dt]) : 0.f);
        }
        float l0al = bflo(l0a), l0bl = bflo(l0b), l1al = bflo(l1a), l1bl = bflo(l1b);
        float l0ah = bfhi(l0a), l0bh = bfhi(l0b), l1ah = bfhi(l1a), l1bh = bfhi(l1b);

        float rl = 2.f * xm_l + um_l + (l0bl + l0al) + qgelu2(l0bl - l0al)
                                     + (l1bl + l1al) + qgelu2(l1bl - l1al);
        float rh = 2.f * xm_h + um_h + (l0bh + l0ah) + qgelu2(l0bh - l0ah)
                                     + (l1bh + l1ah) + qgelu2(l1bh - l1ah);
        outp[(size_t)(o    ) * T_LEN] = rl;
        outp[(size_t)(o + 1) * T_LEN] = rh;
    }
}

extern "C" void kernel_launch(void* const* d_in, const int* in_sizes, int n_in,
                              void* d_out, int out_size, void* d_ws, size_t ws_size,
                              hipStream_t stream) {
    const float* x    = (const float*)d_in[0];
    const float* w    = (const float*)d_in[1];
    const float* bias = (const float*)d_in[2];
    float* out        = (float*)d_out;
    ushort_t* wold    = (ushort_t*)d_ws;                          // 212,992 B
    ushort_t* wnew    = (ushort_t*)((char*)d_ws + WS_WNEW_OFF);   // 327,680 B

    hipLaunchKernelGGL(convert_w_kernel, dim3(32), dim3(256), 0, stream, w, wold, wnew);
    hipLaunchKernelGGL(fused_int_kernel, dim3(N_INT), dim3(256), 0, stream,
                       x, wnew, bias, out);
    hipLaunchKernelGGL(fused_bnd_kernel, dim3(64), dim3(256), 0, stream,
                       x, wold, bias, out);
}

// Round 9
// 89.111 us; speedup vs baseline: 1.4185x; 1.4092x over previous
//
#include <hip/hip_runtime.h>
#include <hip/hip_bf16.h>

typedef __attribute__((ext_vector_type(4))) float f32x4;
typedef __attribute__((ext_vector_type(8))) short bf16x8;
typedef unsigned short ushort_t;

#define T_LEN 8192
#define N_REFL 8187              // last valid phase index (phase arrays have 8188 elems)
#define POSTRIDE 66              // u16 per phase row (boundary path only)
#define PH_U16 (80 * POSTRIDE)   // 5280 u16 per phase (boundary path only)
#define N_INT 4032               // interior blocks: 126 tiles * 2 g * 16 b
#define WS_WPK_OFF 262144        // wpk offset in ws (wold occupies first 212,992 B)

__device__ __forceinline__ ushort_t f2bf(float f) {
    union { float f; unsigned u; } a; a.f = f;
    unsigned r = a.u + 0x7FFF + ((a.u >> 16) & 1);
    return (ushort_t)(r >> 16);
}

union bf2u { __hip_bfloat162 h; unsigned u; ushort_t s[2]; };

__device__ __forceinline__ unsigned pack_bf2(float a, float b) {
    bf2u x; x.h = __float22bfloat162_rn(make_float2(a, b));  // v_cvt_pk_bf16_f32
    return x.u;
}
__device__ __forceinline__ float bflo(unsigned u) {
    union { unsigned u; float f; } x; x.u = u << 16; return x.f;
}
__device__ __forceinline__ float bfhi(unsigned u) {
    union { unsigned u; float f; } x; x.u = u & 0xffff0000u; return x.f;
}
__device__ __forceinline__ float qgelu(float d) {
    return __fdividef(d, 1.f + __expf(-1.702f * d));
}
__device__ __forceinline__ float rot_lane(float v, int byteIdx) {
    int r = __builtin_amdgcn_ds_bpermute(byteIdx, __builtin_bit_cast(int, v));
    return __builtin_bit_cast(float, r);
}

// ---------------------------------------------------------------------------
// Part A: wold[tap][o][c] bf16 (boundary kernel).
// Part B: wpk[g][wv][fid][lane][8] bf16 — per-lane MFMA fragment layout so each
//         weight-load instruction reads 1KB CONTIGUOUS (16 lines, not 32).
//         fid = 3j+phase, j=(u,h) pair 0..9; phase 0=A(tap 3u),1=L0(3u+2),2=L1(3u+1).
__global__ void convert_w_kernel(const float* __restrict__ w,
                                 ushort_t* __restrict__ wold,
                                 ushort_t* __restrict__ wpk) {
    int bid = blockIdx.x;
    int tid = threadIdx.x;
    if (bid < 416) {
        int idx = bid * 256 + tid;
        if (idx >= 128 * 64 * 13) return;
        int tap = idx % 13;
        int c   = (idx / 13) & 63;
        int o   = idx / (13 * 64);
        wold[(tap * 128 + o) * 64 + c] = f2bf(w[idx]);
    } else {
        int e0   = (bid - 416) * 256 + tid;      // 0 .. 15359
        int lane = e0 & 63;
        int rest = e0 >> 6;                       // g*120 + wv*30 + fid
        int fid  = rest % 30;
        int wv   = (rest / 30) & 3;
        int g    = rest / 120;
        int j = fid / 3, phase = fid % 3;
        int u = j >> 1, h = j & 1;
        int row = lane & 15, kb = lane >> 4;
        int wo  = g * 64 + wv * 16 + row;
        int tap = 3 * u + ((phase == 0) ? 0 : (phase == 1) ? 2 : 1);
        bool zero = (phase != 0) && (u == 4);
        ushort_t* dst = wpk + (size_t)e0 * 8;
        #pragma unroll
        for (int e = 0; e < 8; ++e) {
            int c = h * 32 + kb * 8 + e;
            float v = zero ? 0.f : w[((size_t)wo * 64 + c) * 13 + tap];
            dst[e] = f2bf(v);
        }
    }
}

// ---------------------------------------------------------------------------
// Interior kernel (tiles 1..126): R3 structure verbatim; only the weight loads
// changed to the packed per-lane layout (coalesced 1KB per instruction).
__global__ __launch_bounds__(256, 4)
void fused_int_kernel(const float* __restrict__ x, const ushort_t* __restrict__ wpk,
                      const float* __restrict__ bias, float* __restrict__ out) {
    __shared__ ushort_t xs[88 * 64];    // 11,264 B, XOR-swizzled

    const int bx   = blockIdx.x;
    const int tid  = threadIdx.x;
    const int lane = tid & 63;
    const int wv   = tid >> 6;
    const int row  = lane & 15;
    const int kb   = lane >> 4;

    const int gb   = bx / 126;
    const int tile = 1 + (bx - gb * 126);
    const int g    = gb & 1;
    const int b    = gb >> 1;
    const int t0   = tile * 64;
    const int mbase = t0 - 8;            // in-range 56..8056 for all interior tiles

    // ---- stage x[group ch][mbase..mbase+87] -> xs[s][c^((s&7)<<3)] bf16 ----
    const float* xg = x + ((size_t)b * 128 + (size_t)g * 64) * T_LEN;
    for (int cid = tid; cid < 64 * 22; cid += 256) {
        int c  = cid & 63;
        int s0 = (cid >> 6) * 4;
        float4 v = *(const float4*)(xg + (size_t)c * T_LEN + (mbase + s0));
        unsigned p01 = pack_bf2(v.x, v.y);
        unsigned p23 = pack_bf2(v.z, v.w);
        xs[(s0 + 0) * 64 + (c ^ (((s0 + 0) & 7) << 3))] = (ushort_t)(p01 & 0xffff);
        xs[(s0 + 1) * 64 + (c ^ (((s0 + 1) & 7) << 3))] = (ushort_t)(p01 >> 16);
        xs[(s0 + 2) * 64 + (c ^ (((s0 + 2) & 7) << 3))] = (ushort_t)(p23 & 0xffff);
        xs[(s0 + 3) * 64 + (c ^ (((s0 + 3) & 7) << 3))] = (ushort_t)(p23 >> 16);
    }
    const int wo = g * 64 + wv * 16 + row;
    const float bo = bias[wo];
    // per-lane packed weight base: fragment f lives at wp + f*512 (64 lanes * 8 u16)
    const ushort_t* wp = wpk + (((size_t)(g * 4 + wv)) * 30 * 64 + lane) * 8;
    __syncthreads();

    f32x4 accA[5], accL0[5], accL1[5];
    #pragma unroll
    for (int q = 0; q < 5; ++q) {
        accA[q]  = (f32x4){0.f, 0.f, 0.f, 0.f};
        accL0[q] = (f32x4){0.f, 0.f, 0.f, 0.f};
        accL1[q] = (f32x4){0.f, 0.f, 0.f, 0.f};
    }

    #pragma unroll
    for (int j = 0; j < 10; ++j) {
        const int u = j >> 1, h = j & 1;
        bf16x8 wf0 = *(const bf16x8*)(wp + (3 * j + 0) * 512);
        bf16x8 wf1 = {}, wf2 = {};
        if (u < 4) {
            wf1 = *(const bf16x8*)(wp + (3 * j + 1) * 512);
            wf2 = *(const bf16x8*)(wp + (3 * j + 2) * 512);
        }
        #pragma unroll
        for (int q = 0; q < 5; ++q) {
            int s = 16 * q + row + u;
            const bf16x8 xa = *(const bf16x8*)(xs + s * 64 + ((h * 32 + kb * 8) ^ ((s & 7) << 3)));
            accA[q] = __builtin_amdgcn_mfma_f32_16x16x32_bf16(xa, wf0, accA[q], 0, 0, 0);
            if (u < 4) {
                accL0[q] = __builtin_amdgcn_mfma_f32_16x16x32_bf16(xa, wf1, accL0[q], 0, 0, 0);
                accL1[q] = __builtin_amdgcn_mfma_f32_16x16x32_bf16(xa, wf2, accL1[q], 0, 0, 0);
            }
        }
    }

    // ---- R3 in-register epilogue (verbatim) ----
    const int upIdx = ((lane + 16) & 63) << 2;
    const int dnIdx = ((lane + 48) & 63) << 2;

    float u0[6], u1[6], d2m[5], d3m[5], lu[6], lv[6];
    #pragma unroll
    for (int q = 0; q < 5; ++q) {
        u0[q]  = rot_lane(accA[q][0], upIdx);
        u1[q]  = rot_lane(accA[q][1], upIdx);
        d2m[q] = rot_lane(accA[q][2], dnIdx);
        d3m[q] = rot_lane(accA[q][3], dnIdx);
        lu[q]  = rot_lane(accL0[q][0], upIdx);
        lv[q]  = rot_lane(accL1[q][0], upIdx);
    }
    u0[5] = 0.f; u1[5] = 0.f; lu[5] = 0.f; lv[5] = 0.f;

    const bool kbLT3 = (kb < 3);
    const bool kbGT0 = (kb > 0);
    const float c7bo = 7.f * bo;
    float* outBase = out + ((size_t)(b * 128 + wo)) * T_LEN + (t0 - 6 + 4 * kb);

    #pragma unroll
    for (int q = 0; q < 5; ++q) {
        #pragma unroll
        for (int r = 0; r < 4; ++r) {
            float A0 = accA[q][r];
            float Ap1 = (r < 3) ? accA[q][r + 1] : (kbLT3 ? u0[q] : u0[q + 1]);
            float Ap2 = (r == 0) ? accA[q][2]
                      : (r == 1) ? accA[q][3]
                      : (r == 2) ? (kbLT3 ? u0[q] : u0[q + 1])
                                 : (kbLT3 ? u1[q] : u1[q + 1]);
            float Am1 = (r > 0) ? accA[q][r - 1]
                                : (kbGT0 ? d3m[q] : (q > 0 ? d3m[q - 1] : 0.f));
            float Am2 = (r == 2) ? accA[q][0]
                      : (r == 3) ? accA[q][1]
                      : (r == 1) ? (kbGT0 ? d3m[q] : (q > 0 ? d3m[q - 1] : 0.f))
                                 : (kbGT0 ? d2m[q] : (q > 0 ? d2m[q - 1] : 0.f));
            float L0a = accL0[q][r];
            float L0b = (r < 3) ? accL0[q][r + 1] : (kbLT3 ? lu[q] : lu[q + 1]);
            float L1a = accL1[q][r];
            float L1b = (r < 3) ? accL1[q][r + 1] : (kbLT3 ? lv[q] : lv[q + 1]);

            float um = fmaxf(fmaxf(fmaxf(Am2, Am1), fmaxf(Ap1, Ap2)), A0);
            float res = 2.f * A0 + um + c7bo + (L0b + L0a) + (L1b + L1a)
                      + qgelu(L0b - L0a) + qgelu(L1b - L1a);

            bool ok = true;
            if (q == 0) ok = (4 * kb + r) >= 6;
            if (q == 4) ok = (4 * kb + r) <= 5;
            if (ok) outBase[16 * q + r] = res;
        }
    }
}

// ---------------------------------------------------------------------------
// Boundary kernel (tiles 0 and 127, 64 blocks): proven R3 LDS-phase path.
__global__ __launch_bounds__(256, 4)
void fused_bnd_kernel(const float* __restrict__ x, const ushort_t* __restrict__ wbf,
                      const float* __restrict__ bias, float* __restrict__ out) {
    __shared__ ushort_t smem[3 * PH_U16];   // 31,680 B
    ushort_t* xs = smem;

    const int idx  = blockIdx.x;
    const int tid  = threadIdx.x;
    const int lane = tid & 63;
    const int wv   = tid >> 6;
    const int row  = lane & 15;
    const int kb   = lane >> 4;

    const int tile = (idx & 1) ? 127 : 0;
    const int g    = (idx >> 1) & 1;
    const int b    = idx >> 2;
    const int t0    = tile * 64;
    const int mbase = t0 - 8;

    const float* xg = x + ((size_t)b * 128 + (size_t)g * 64) * T_LEN;
    for (int cid = tid; cid < 64 * 22; cid += 256) {
        int c  = cid & 63;
        int s0 = (cid >> 6) * 4;
        int m0 = mbase + s0;
        const float* src = xg + (size_t)c * T_LEN + m0;
        float v0, v1, v2, v3;
        if (m0 >= 0 && m0 + 3 < T_LEN) {
            float4 v = *(const float4*)src;
            v0 = v.x; v1 = v.y; v2 = v.z; v3 = v.w;
        } else {
            v0 = ((unsigned)(m0 + 0) < (unsigned)T_LEN) ? src[0] : 0.f;
            v1 = ((unsigned)(m0 + 1) < (unsigned)T_LEN) ? src[1] : 0.f;
            v2 = ((unsigned)(m0 + 2) < (unsigned)T_LEN) ? src[2] : 0.f;
            v3 = ((unsigned)(m0 + 3) < (unsigned)T_LEN) ? src[3] : 0.f;
        }
        unsigned p01 = pack_bf2(v0, v1);
        unsigned p23 = pack_bf2(v2, v3);
        xs[(s0 + 0) * 64 + (c ^ (((s0 + 0) & 7) << 3))] = (ushort_t)(p01 & 0xffff);
        xs[(s0 + 1) * 64 + (c ^ (((s0 + 1) & 7) << 3))] = (ushort_t)(p01 >> 16);
        xs[(s0 + 2) * 64 + (c ^ (((s0 + 2) & 7) << 3))] = (ushort_t)(p23 & 0xffff);
        xs[(s0 + 3) * 64 + (c ^ (((s0 + 3) & 7) << 3))] = (ushort_t)(p23 >> 16);
    }
    __syncthreads();

    f32x4 accA[5], accL0[5], accL1[5];
    #pragma unroll
    for (int q = 0; q < 5; ++q) {
        accA[q]  = (f32x4){0.f, 0.f, 0.f, 0.f};
        accL0[q] = (f32x4){0.f, 0.f, 0.f, 0.f};
        accL1[q] = (f32x4){0.f, 0.f, 0.f, 0.f};
    }
    const int wo = g * 64 + wv * 16 + row;

    #pragma unroll
    for (int u = 0; u < 5; ++u) {
        #pragma unroll
        for (int h = 0; h < 2; ++h) {
            bf16x8 wf0 = *(const bf16x8*)(wbf + ((3 * u + 0) * 128 + wo) * 64 + h * 32 + kb * 8);
            bf16x8 wf1 = {}, wf2 = {};
            if (u < 4) {
                wf1 = *(const bf16x8*)(wbf + ((3 * u + 2) * 128 + wo) * 64 + h * 32 + kb * 8);
                wf2 = *(const bf16x8*)(wbf + ((3 * u + 1) * 128 + wo) * 64 + h * 32 + kb * 8);
            }
            #pragma unroll
            for (int q = 0; q < 5; ++q) {
                int s = 16 * q + row + u;
                const bf16x8 xa = *(const bf16x8*)(xs + s * 64 + ((h * 32 + kb * 8) ^ ((s & 7) << 3)));
                accA[q] = __builtin_amdgcn_mfma_f32_16x16x32_bf16(xa, wf0, accA[q], 0, 0, 0);
                if (u < 4) {
                    accL0[q] = __builtin_amdgcn_mfma_f32_16x16x32_bf16(xa, wf1, accL0[q], 0, 0, 0);
                    accL1[q] = __builtin_amdgcn_mfma_f32_16x16x32_bf16(xa, wf2, accL1[q], 0, 0, 0);
                }
            }
        }
    }
    const float bo = bias[wo];
    __syncthreads();

    #pragma unroll
    for (int q = 0; q < 5; ++q) {
        #pragma unroll
        for (int p = 0; p < 3; ++p) {
            const f32x4& a = (p == 0) ? accA[q] : (p == 1) ? accL0[q] : accL1[q];
            unsigned pa = pack_bf2(a[0] + bo, a[1] + bo);
            unsigned pb = pack_bf2(a[2] + bo, a[3] + bo);
            int base = p * PH_U16 + (16 * q + kb * 4) * POSTRIDE + wv * 16 + row;
            smem[base + 0 * POSTRIDE] = (ushort_t)(pa & 0xffff);
            smem[base + 1 * POSTRIDE] = (ushort_t)(pa >> 16);
            smem[base + 2 * POSTRIDE] = (ushort_t)(pb & 0xffff);
            smem[base + 3 * POSTRIDE] = (ushort_t)(pb >> 16);
        }
    }
    __syncthreads();

    const int tl = tid & 63;
    const int wq = tid >> 6;
    const int t  = t0 + tl;
    const ushort_t* phA  = smem;
    const ushort_t* phL0 = smem + PH_U16;
    const ushort_t* phL1 = smem + 2 * PH_U16;
    float* outp = out + ((size_t)b * 128 + (size_t)g * 64) * T_LEN + t;

    int  s5[5];
    bool in5[5];
    #pragma unroll
    for (int dt = 0; dt < 5; ++dt) {
        int tp = t + dt - 2;
        in5[dt] = ((unsigned)tp < (unsigned)T_LEN);
        int ix = tp - 2;
        ix = (ix < 0) ? -ix : ix;
        ix = (ix > N_REFL) ? (2 * N_REFL - ix) : ix;
        s5[dt] = ix - mbase;
    }
    const int sC = s5[2];
    for (int i = 0; i < 8; ++i) {
        int o = 2 * wq + 8 * i;
        unsigned av[5];
        #pragma unroll
        for (int dt = 0; dt < 5; ++dt)
            av[dt] = *(const unsigned*)(phA + s5[dt] * POSTRIDE + o);
        unsigned l0a = *(const unsigned*)(phL0 + (sC    ) * POSTRIDE + o);
        unsigned l0b = *(const unsigned*)(phL0 + (sC + 1) * POSTRIDE + o);
        unsigned l1a = *(const unsigned*)(phL1 + (sC    ) * POSTRIDE + o);
        unsigned l1b = *(const unsigned*)(phL1 + (sC + 1) * POSTRIDE + o);

        float xm_l = bflo(av[2]), xm_h = bfhi(av[2]);
        float um_l = -1e30f, um_h = -1e30f;
        #pragma unroll
        for (int dt = 0; dt < 5; ++dt) {
            um_l = fmaxf(um_l, in5[dt] ? bflo(av[dt]) : 0.f);
            um_h = fmaxf(um_h, in5[dt] ? bfhi(av[dt]) : 0.f);
        }
        float l0al = bflo(l0a), l0bl = bflo(l0b), l1al = bflo(l1a), l1bl = bflo(l1b);
        float l0ah = bfhi(l0a), l0bh = bfhi(l0b), l1ah = bfhi(l1a), l1bh = bfhi(l1b);

        float rl = 2.f * xm_l + um_l + (l0bl + l0al) + qgelu(l0bl - l0al)
                                     + (l1bl + l1al) + qgelu(l1bl - l1al);
        float rh = 2.f * xm_h + um_h + (l0bh + l0ah) + qgelu(l0bh - l0ah)
                                     + (l1bh + l1ah) + qgelu(l1bh - l1ah);
        outp[(size_t)(o    ) * T_LEN] = rl;
        outp[(size_t)(o + 1) * T_LEN] = rh;
    }
}

extern "C" void kernel_launch(void* const* d_in, const int* in_sizes, int n_in,
                              void* d_out, int out_size, void* d_ws, size_t ws_size,
                              hipStream_t stream) {
    const float* x    = (const float*)d_in[0];
    const float* w    = (const float*)d_in[1];
    const float* bias = (const float*)d_in[2];
    float* out        = (float*)d_out;
    ushort_t* wold    = (ushort_t*)d_ws;                         // 212,992 B
    ushort_t* wpk     = (ushort_t*)((char*)d_ws + WS_WPK_OFF);   // 245,760 B

    hipLaunchKernelGGL(convert_w_kernel, dim3(416 + 60), dim3(256), 0, stream,
                       w, wold, wpk);
    hipLaunchKernelGGL(fused_int_kernel, dim3(N_INT), dim3(256), 0, stream,
                       x, wpk, bias, out);
    hipLaunchKernelGGL(fused_bnd_kernel, dim3(64), dim3(256), 0, stream,
                       x, wold, bias, out);
}